// Round 6
// baseline (20.958 us; speedup 1.0000x reference)
//
#include <hip/hip_runtime.h>
#include <hip/hip_bf16.h>
#include <math.h>

// Problem constants (from reference setup_inputs)
#define BATCH   512          // bs * n_vars = 64 * 8
#define KP      3            // k_positive
#define KN      16           // k_negative
#define KTOT    (KP + KN)    // 19
#define PD      8192         // P * D = 64 * 128
#define INV_T   50.0f        // 1 / temperature (0.02)

#define SPLIT   8            // d-slices per sample == #XCDs (part == XCD id)
#define CHUNK   (PD / SPLIT) // 1024 floats per slice (4 KB per row)
#define THREADS 256          // 256 threads * 4 floats = 1024 (dense 1 f32x4/thread)
#define GROUPS  2            // samples per block -> grid = 2048 = 8 blocks/CU, 1 round
#define HALF    (BATCH / GROUPS)

typedef float f32x4 __attribute__((ext_vector_type(4)));

__global__ __launch_bounds__(THREADS)
void agg_rebuild_kernel(const float* __restrict__ sim,
                        const float* __restrict__ p_enc,
                        const int*   __restrict__ neg_idx,
                        float*       __restrict__ out) {
    const int part = blockIdx.x & (SPLIT - 1); // d-slice == XCD id (round-robin)
    const int bg   = blockIdx.x >> 3;          // sample-group index
    const int d    = part * CHUNK + threadIdx.x * 4;

    #pragma unroll
    for (int s = 0; s < GROUPS; ++s) {
        const int b = bg + s * HALF;           // block-uniform sample index

        // softmax over 19 temperature-scaled scores, redundantly in all lanes
        // from uniform addresses (scalarizes to s_load; no LDS, no barriers).
        float w[KTOT];
        float m = -INFINITY;
        #pragma unroll
        for (int k = 0; k < KTOT; ++k) {
            w[k] = sim[b * KTOT + k] * INV_T;
            m = fmaxf(m, w[k]);
        }
        float sum = 0.0f;
        #pragma unroll
        for (int k = 0; k < KTOT; ++k) {
            w[k] = __expf(w[k] - m);
            sum += w[k];
        }
        const float inv = 1.0f / sum;

        // row offsets (uniform 32-bit element offsets; base stays in SGPR pair)
        int rowoff[KTOT];
        #pragma unroll
        for (int k = 0; k < KP; ++k)
            rowoff[k] = (BATCH + b * KP + k) * PD;
        #pragma unroll
        for (int k = 0; k < KN; ++k)
            rowoff[KP + k] = neg_idx[b * KN + k] * PD;

        // weighted sum of 19 rows, one dense f32x4 per thread
        // (each wave load instruction covers one contiguous 1 KB segment)
        f32x4 acc = {0.f, 0.f, 0.f, 0.f};
        #pragma unroll
        for (int k = 0; k < KTOT; ++k) {
            const f32x4 x = *reinterpret_cast<const f32x4*>(p_enc + rowoff[k] + d);
            acc += (w[k] * inv) * x;
        }

        *reinterpret_cast<f32x4*>(out + (size_t)b * PD + d) = acc;
    }
}

extern "C" void kernel_launch(void* const* d_in, const int* in_sizes, int n_in,
                              void* d_out, int out_size, void* d_ws, size_t ws_size,
                              hipStream_t stream) {
    const float* sim     = (const float*)d_in[0];   // [B, 19]
    const float* p_enc   = (const float*)d_in[1];   // [B*(1+KP), P, D]
    const int*   neg_idx = (const int*)d_in[2];     // [B, KN]
    float*       out     = (float*)d_out;           // [B, P, D]

    dim3 grid((BATCH / GROUPS) * SPLIT);            // 2048 blocks
    dim3 block(THREADS);
    agg_rebuild_kernel<<<grid, block, 0, stream>>>(sim, p_enc, neg_idx, out);
}